// Round 11
// baseline (443.444 us; speedup 1.0000x reference)
//
#include <hip/hip_runtime.h>
#include <math.h>

// Problem constants
#define Bd   4
#define Md   8192
#define Dd   64
#define Sd   1024
#define H0d  32
#define H1d  128

// d_out layout (float offsets), return order:
// sampled_points (B,S,3) | grouped_points (B,S,32,3) | sampled_feature (B,S,64)
// | grouped_feature (B,S,32,64) | Qg (B,S,M)
#define OFF_SP 0
#define OFF_GP 12288
#define OFF_SF 405504
#define OFF_GF 667648          // holds f32 h1T scratch [b][k][m] (16.8MB) until k3 overwrites
#define OFF_QG 9056256         // holds u32 sortable-Q keys [B][S][M] until one-hot overwrite

#define CAP 512                // candidate cap (expected n ~150)

// order-preserving float -> sortable u32
__device__ __forceinline__ unsigned f2u(float f) {
    unsigned v = __float_as_uint(f);
    return (v & 0x80000000u) ? ~v : (v | 0x80000000u);
}

// ---------------------------------------------------------------------------
// K1: per-point MLP (f64 internal math, f32 output), h1T[b][k][m].
// 4-way j-split, 512 blocks. [unchanged, verified]
// ---------------------------------------------------------------------------
__global__ __launch_bounds__(256) void k1_mlp(
    const float* __restrict__ coord,
    const float* __restrict__ w0,
    const float* __restrict__ g0, const float* __restrict__ be0,
    const float* __restrict__ mu0, const float* __restrict__ va0,
    const float* __restrict__ w1,
    const float* __restrict__ g1, const float* __restrict__ be1,
    const float* __restrict__ mu1, const float* __restrict__ va1,
    float* __restrict__ h1T)
{
    const int jg = blockIdx.x & 3;           // j-range [jg*32, jg*32+32)
    const int j0 = jg * 32;
    __shared__ double W1[H0d * 32];
    __shared__ double W0[5 * H0d];
    __shared__ double MU0[H0d], RS0[H0d], BE0[H0d];
    __shared__ double MU1[32], RS1[32], BE1[32];
    const int t = threadIdx.x;
    for (int e = t; e < H0d * 32; e += 256) {
        int i = e >> 5, jc = e & 31;
        W1[e] = (double)w1[i * H1d + j0 + jc];
    }
    if (t < 5 * H0d) W0[t] = (double)w0[t];
    if (t < H0d) {
        MU0[t] = (double)mu0[t];
        RS0[t] = (double)g0[t] / sqrt((double)va0[t] + 1e-5);
        BE0[t] = (double)be0[t];
    }
    if (t >= 192 && t < 224) {
        int j = t - 192;
        MU1[j] = (double)mu1[j0 + j];
        RS1[j] = (double)g1[j0 + j] / sqrt((double)va1[j0 + j] + 1e-5);
        BE1[j] = (double)be1[j0 + j];
    }
    __syncthreads();

    const int p = (blockIdx.x >> 2) * 256 + t;   // 0..32767  (= b*M + m)
    const double x = (double)coord[p * 3 + 0];
    const double y = (double)coord[p * 3 + 1];
    const double z = (double)coord[p * 3 + 2];
    const double r  = sqrt(x * x + y * y + z * z);
    const double th = acos(z / r);
    const double fi = atan2(y, x);

    double h0[H0d];
    #pragma unroll
    for (int i = 0; i < H0d; i++) {
        double a = x * W0[i] + y * W0[H0d + i] + z * W0[2 * H0d + i]
                 + th * W0[3 * H0d + i] + fi * W0[4 * H0d + i];
        a = (a - MU0[i]) * RS0[i] + BE0[i];
        h0[i] = a > 0.0 ? a : 0.0;
    }
    float* o = h1T + (size_t)(p >> 13) * (H1d * Md) + (p & (Md - 1));
    for (int jc = 0; jc < 32; jc += 2) {
        double a0 = 0.0, a1 = 0.0;
        #pragma unroll
        for (int i = 0; i < H0d; i++) {
            double h = h0[i];
            a0 += h * W1[i * 32 + jc];
            a1 += h * W1[i * 32 + jc + 1];
        }
        a0 = (a0 - MU1[jc]) * RS1[jc] + BE1[jc];             a0 = a0 > 0.0 ? a0 : 0.0;
        a1 = (a1 - MU1[jc + 1]) * RS1[jc + 1] + BE1[jc + 1]; a1 = a1 > 0.0 ? a1 : 0.0;
        o[(size_t)(j0 + jc) * Md]     = (float)a0;
        o[(size_t)(j0 + jc + 1) * Md] = (float)a1;
    }
}

// ---------------------------------------------------------------------------
// K2: f32 GEMM + sigmoid epilogue + gumbel-argmax contribution.
// acc loop untouched -> logits bitwise identical; q = 1/(1+expf(-acc)) same
// values as the verified round-10 kernel; uq store identical.
// NEW: per output row-chunk, compute u64 gumbel keys (f2u(q+g)<<32 | 8191-m),
// shfl-reduce over the 16-lane tm-group, atomicMax into ws[row]. Max over the
// identical key multiset == round-10's per-row argmax winner, order-free.
// Epilogue si-loop is unroll-1 to cap register pressure (round-10 regression).
// ---------------------------------------------------------------------------
__global__ __launch_bounds__(256, 4) void k2_gemm(
    const float* __restrict__ h1T,
    const float* __restrict__ w2,
    const float* __restrict__ gum,
    unsigned* __restrict__ uqout,
    unsigned long long* __restrict__ ws)
{
    __shared__ float As[32][128];            // 16 KB
    __shared__ float Bs[32][128];            // 16 KB
    const int bx = blockIdx.x, b = blockIdx.y;
    const int mtile = bx & 63, stile = bx >> 6;   // mtile fast: same-A blocks on one XCD
    const int m0 = mtile * 128, s0 = stile * 128;
    const int t = threadIdx.x;
    const int tm = t & 15, tn = t >> 4;

    float acc[8][8] = {};

    for (int kt = 0; kt < 4; kt++) {
        const float* Ag = h1T + ((size_t)b * H1d + kt * 32) * Md + m0;
        const float* Bg = w2 + (size_t)(kt * 32) * Sd + s0;
        #pragma unroll
        for (int i = 0; i < 4; i++) {
            int idx = t + i * 256;
            int kk = idx >> 5, c = idx & 31;
            *(float4*)&As[kk][c * 4] = *(const float4*)&Ag[(size_t)kk * Md + c * 4];
            *(float4*)&Bs[kk][c * 4] = *(const float4*)&Bg[(size_t)kk * Sd + c * 4];
        }
        __syncthreads();

        #pragma unroll 8
        for (int k = 0; k < 32; k++) {
            float a_[8], b_[8];
            *(float4*)&a_[0] = *(const float4*)&As[k][tm * 4];
            *(float4*)&a_[4] = *(const float4*)&As[k][64 + tm * 4];
            *(float4*)&b_[0] = *(const float4*)&Bs[k][tn * 4];
            *(float4*)&b_[4] = *(const float4*)&Bs[k][64 + tn * 4];
            #pragma unroll
            for (int si = 0; si < 8; si++)
                #pragma unroll
                for (int mi = 0; mi < 8; mi++)
                    acc[si][mi] += b_[si] * a_[mi];
        }
        __syncthreads();
    }

    #pragma unroll 1
    for (int si = 0; si < 8; si++) {
        const int s = s0 + (si >> 2) * 64 + tn * 4 + (si & 3);
        const int row = b * Sd + s;
        // sigmoid (libm expf — bit-identical to verified rounds)
        float q0 = 1.0f / (1.0f + expf(-acc[si][0]));
        float q1 = 1.0f / (1.0f + expf(-acc[si][1]));
        float q2 = 1.0f / (1.0f + expf(-acc[si][2]));
        float q3 = 1.0f / (1.0f + expf(-acc[si][3]));
        float q4 = 1.0f / (1.0f + expf(-acc[si][4]));
        float q5 = 1.0f / (1.0f + expf(-acc[si][5]));
        float q6 = 1.0f / (1.0f + expf(-acc[si][6]));
        float q7 = 1.0f / (1.0f + expf(-acc[si][7]));
        // store sortable keys
        unsigned* orow = uqout + (size_t)row * Md + m0;
        uint4 w0v = make_uint4(f2u(q0), f2u(q1), f2u(q2), f2u(q3));
        uint4 w1v = make_uint4(f2u(q4), f2u(q5), f2u(q6), f2u(q7));
        *(uint4*)&orow[tm * 4]      = w0v;
        *(uint4*)&orow[64 + tm * 4] = w1v;
        // gumbel keys (cold gumbel read hides under the FMA-bound kernel)
        const float* gr = gum + (size_t)row * Md + m0;
        float4 ga = *(const float4*)&gr[tm * 4];
        float4 gb = *(const float4*)&gr[64 + tm * 4];
        unsigned long long kmax;
        {
            int mb = m0 + tm * 4;
            unsigned long long k0 = ((unsigned long long)f2u(q0 + ga.x) << 32) | (unsigned)(Md - 1 - (mb + 0));
            unsigned long long k1 = ((unsigned long long)f2u(q1 + ga.y) << 32) | (unsigned)(Md - 1 - (mb + 1));
            unsigned long long k2 = ((unsigned long long)f2u(q2 + ga.z) << 32) | (unsigned)(Md - 1 - (mb + 2));
            unsigned long long k3 = ((unsigned long long)f2u(q3 + ga.w) << 32) | (unsigned)(Md - 1 - (mb + 3));
            unsigned long long k4 = ((unsigned long long)f2u(q4 + gb.x) << 32) | (unsigned)(Md - 1 - (mb + 64));
            unsigned long long k5 = ((unsigned long long)f2u(q5 + gb.y) << 32) | (unsigned)(Md - 1 - (mb + 65));
            unsigned long long k6 = ((unsigned long long)f2u(q6 + gb.z) << 32) | (unsigned)(Md - 1 - (mb + 66));
            unsigned long long k7 = ((unsigned long long)f2u(q7 + gb.w) << 32) | (unsigned)(Md - 1 - (mb + 67));
            kmax = k0 > k1 ? k0 : k1;
            if (k2 > kmax) kmax = k2;
            if (k3 > kmax) kmax = k3;
            if (k4 > kmax) kmax = k4;
            if (k5 > kmax) kmax = k5;
            if (k6 > kmax) kmax = k6;
            if (k7 > kmax) kmax = k7;
        }
        #pragma unroll
        for (int o = 1; o < 16; o <<= 1) {
            unsigned long long other = __shfl_xor(kmax, o);
            if (other > kmax) kmax = other;
        }
        if (tm == 0) atomicMax(&ws[row], kmax);
    }
}

// ---------------------------------------------------------------------------
// K3 (fused, slim): selection + one-hot + gather, one block per (b,s) row.
// No gumbel work (argmax precomputed in ws by k2). uq input is L3-resident.
// Threshold filter + rank-count machinery byte-identical to verified rounds;
// guard falls back to the verified iterative extractor.
// ---------------------------------------------------------------------------
__global__ __launch_bounds__(256) void k3_fused(
    unsigned* __restrict__ uqbuf,            // row r read, then overwritten with Qg one-hot
    const unsigned long long* __restrict__ ws,
    const float* __restrict__ coord,
    const float* __restrict__ feat,
    float* __restrict__ out)
{
    const int r = blockIdx.x;                // 0..4095
    const int b = r >> 10;
    const int t = threadIdx.x;
    const int lane = t & 63, wav = t >> 6;
    const uint4* L4 = (const uint4*)(uqbuf + (size_t)r * Md);

    __shared__ unsigned long long wred[2][4];
    __shared__ unsigned long long ck[CAP];
    __shared__ unsigned swT[4];
    __shared__ int cnt;
    __shared__ int order[32];
    __shared__ int am_s;

    // ---- load keys (16B/lane) ----
    unsigned uq[32];
    #pragma unroll
    for (int j = 0; j < 8; j++) {
        uint4 v = L4[j * 256 + t];
        uq[j * 4 + 0] = v.x;
        uq[j * 4 + 1] = v.y;
        uq[j * 4 + 2] = v.z;
        uq[j * 4 + 3] = v.w;
    }
    if (t == 0) {
        cnt = 0;
        am_s = Md - 1 - (int)(ws[r] & 0xFFFFFFFFull);
    }

    // ---- per-thread max, wave bitonic sort of 64 lane-maxima -> threshold T ----
    unsigned pm = 0u;
    #pragma unroll
    for (int i = 0; i < 32; i++) pm = max(pm, uq[i]);
    unsigned v = pm;
    #pragma unroll
    for (int k = 2; k <= 64; k <<= 1) {
        #pragma unroll
        for (int j = k >> 1; j > 0; j >>= 1) {
            unsigned o = __shfl_xor(v, j);
            bool up = ((lane & k) == 0);
            bool lower = ((lane & j) == 0);
            unsigned mn = min(v, o), mx = max(v, o);
            v = (lower == up) ? mn : mx;     // ascending by lane after final pass
        }
    }
    unsigned tw = __shfl(v, 32);             // asc pos 32 = 32nd largest of the wave
    if (lane == 0) swT[wav] = tw;
    __syncthreads();                         // B1: swT, cnt, am_s
    const int am = am_s;
    const unsigned T = max(max(swT[0], swT[1]), max(swT[2], swT[3]));

    // ---- collect candidates >= T ----
    #pragma unroll
    for (int i = 0; i < 32; i++) {
        if (uq[i] >= T) {
            int pos = atomicAdd(&cnt, 1);
            if (pos < CAP) {
                int m = (i >> 2) * 1024 + t * 4 + (i & 3);
                ck[pos] = ((unsigned long long)uq[i] << 32) | (unsigned)(Md - 1 - m);
            }
        }
    }
    __syncthreads();                         // B2: ck, cnt
    const int n = cnt;

    if (n >= 32 && n <= CAP) {
        // ---- fast path: O(n^2) rank-count ----
        for (int j2 = t; j2 < n; j2 += 256) {
            unsigned long long mine = ck[j2];
            int rk = 0;
            for (int i2 = 0; i2 < n; i2++) rk += (ck[i2] > mine) ? 1 : 0;
            if (rk < 32) order[rk] = Md - 1 - (int)(mine & 0xFFFFFFFFull);
        }
    } else {
        // ---- fallback: verified iterative extraction ----
        for (int round = 0; round < 32; round++) {
            unsigned bu = 0u; int bi = 0;
            #pragma unroll
            for (int i = 0; i < 32; i++)
                if (uq[i] > bu) { bu = uq[i]; bi = i; }
            int bm = (bi >> 2) * 1024 + t * 4 + (bi & 3);
            unsigned long long key =
                ((unsigned long long)bu << 32) | (unsigned)(Md - 1 - bm);
            #pragma unroll
            for (int o = 32; o > 0; o >>= 1) {
                unsigned long long other = __shfl_down(key, o);
                if (other > key) key = other;
            }
            const int p = round & 1;
            if (lane == 0) wred[p][wav] = key;
            __syncthreads();
            unsigned long long best = wred[p][0];
            if (wred[p][1] > best) best = wred[p][1];
            if (wred[p][2] > best) best = wred[p][2];
            if (wred[p][3] > best) best = wred[p][3];
            const int m_win = Md - 1 - (int)(best & 0xFFFFFFFFull);
            if (((m_win >> 2) & 255) == t)
                uq[(m_win >> 10) * 4 + (m_win & 3)] = 0u;
            if (t == 0) order[round] = m_win;
        }
    }
    __syncthreads();                         // B3: order[] visible

    // ---- outputs ----
    // Qg one-hot (overwrites this block's own key row)
    {
        const int q4 = am >> 2;
        float4* row = (float4*)(uqbuf + (size_t)r * Md);
        #pragma unroll
        for (int i = 0; i < 8; i++) {
            int idx = i * 256 + t;
            float4 vv = make_float4(0.f, 0.f, 0.f, 0.f);
            if (idx == q4) ((float*)&vv)[am & 3] = 1.0f;
            row[idx] = vv;
        }
    }
    if (t < 3)
        out[OFF_SP + (size_t)r * 3 + t] = coord[((size_t)b * Md + am) * 3 + t];
    if (t >= 32 && t < 128) {
        int e = t - 32;                      // 0..95
        int nn = e / 3, c = e - nn * 3;
        out[OFF_GP + (size_t)r * 96 + e] = coord[((size_t)b * Md + order[nn]) * 3 + c];
    }
    const float4* F4  = (const float4*)feat;          // feat row = 16 float4
    float4* SF4 = (float4*)(out + OFF_SF);
    float4* GF4 = (float4*)(out + OFF_GF);
    if (t < 16) {
        float4 fv = F4[((size_t)b * Md + am) * 16 + t];
        SF4[(size_t)r * 16 + t]  = fv;       // sampled_feature
        GF4[(size_t)r * 512 + t] = fv;       // grouped_feature[.,.,0,:]
    }
    for (int e4 = 16 + t; e4 < 512; e4 += 256) {
        int nn = e4 >> 4, d4 = e4 & 15;
        GF4[(size_t)r * 512 + e4] = F4[((size_t)b * Md + order[nn]) * 16 + d4];
    }
}

// ---------------------------------------------------------------------------
extern "C" void kernel_launch(void* const* d_in, const int* in_sizes, int n_in,
                              void* d_out, int out_size, void* d_ws, size_t ws_size,
                              hipStream_t stream)
{
    (void)in_sizes; (void)n_in; (void)out_size; (void)ws_size;
    const float* coord = (const float*)d_in[0];
    const float* feat  = (const float*)d_in[1];
    const float* gum   = (const float*)d_in[2];
    const float* w0    = (const float*)d_in[3];
    const float* g0    = (const float*)d_in[4];
    const float* be0   = (const float*)d_in[5];
    const float* mu0   = (const float*)d_in[6];
    const float* va0   = (const float*)d_in[7];
    const float* w1    = (const float*)d_in[8];
    const float* g1    = (const float*)d_in[9];
    const float* be1   = (const float*)d_in[10];
    const float* mu1   = (const float*)d_in[11];
    const float* va1   = (const float*)d_in[12];
    const float* w2    = (const float*)d_in[13];

    float*    out  = (float*)d_out;
    float*    h1T  = out + OFF_GF;              // f32 h1T scratch (overwritten by k3 gather)
    unsigned* uqb  = (unsigned*)(out + OFF_QG); // u32 Q keys -> Qg one-hot
    unsigned long long* ws = (unsigned long long*)d_ws;  // 4096 per-row argmax keys

    hipMemsetAsync(d_ws, 0, (size_t)(Bd * Sd) * sizeof(unsigned long long), stream);
    k1_mlp   <<<dim3(512),     dim3(256), 0, stream>>>(coord, w0, g0, be0, mu0, va0,
                                                       w1, g1, be1, mu1, va1, h1T);
    k2_gemm  <<<dim3(512, 4),  dim3(256), 0, stream>>>(h1T, w2, gum, uqb, ws);
    k3_fused <<<dim3(4096),    dim3(256), 0, stream>>>(uqb, ws, coord, feat, out);
}

// Round 12
// 218.020 us; speedup vs baseline: 2.0340x; 2.0340x over previous
//
#include <hip/hip_runtime.h>
#include <math.h>

// Problem constants
#define Bd   4
#define Md   8192
#define Dd   64
#define Sd   1024
#define H0d  32
#define H1d  128

// d_out layout (float offsets), return order:
// sampled_points (B,S,3) | grouped_points (B,S,32,3) | sampled_feature (B,S,64)
// | grouped_feature (B,S,32,64) | Qg (B,S,M)
#define OFF_SP 0
#define OFF_GP 12288
#define OFF_SF 405504
#define OFF_GF 667648          // holds f32 h1T scratch [b][k][m] (16.8MB) until k3 overwrites
#define OFF_QG 9056256         // holds f32 logits [B][S][M] until one-hot overwrite

#define CAP 512                // candidate cap (expected n ~150)

// order-preserving float -> sortable u32
__device__ __forceinline__ unsigned f2u(float f) {
    unsigned v = __float_as_uint(f);
    return (v & 0x80000000u) ? ~v : (v | 0x80000000u);
}

// ---------------------------------------------------------------------------
// K1: per-point MLP (f64 internal math, f32 output), h1T[b][k][m].
// 4-way j-split, 512 blocks — bitwise-identical h1T, verified rounds 10/11.
// ---------------------------------------------------------------------------
__global__ __launch_bounds__(256) void k1_mlp(
    const float* __restrict__ coord,
    const float* __restrict__ w0,
    const float* __restrict__ g0, const float* __restrict__ be0,
    const float* __restrict__ mu0, const float* __restrict__ va0,
    const float* __restrict__ w1,
    const float* __restrict__ g1, const float* __restrict__ be1,
    const float* __restrict__ mu1, const float* __restrict__ va1,
    float* __restrict__ h1T)
{
    const int jg = blockIdx.x & 3;           // j-range [jg*32, jg*32+32)
    const int j0 = jg * 32;
    __shared__ double W1[H0d * 32];
    __shared__ double W0[5 * H0d];
    __shared__ double MU0[H0d], RS0[H0d], BE0[H0d];
    __shared__ double MU1[32], RS1[32], BE1[32];
    const int t = threadIdx.x;
    for (int e = t; e < H0d * 32; e += 256) {
        int i = e >> 5, jc = e & 31;
        W1[e] = (double)w1[i * H1d + j0 + jc];
    }
    if (t < 5 * H0d) W0[t] = (double)w0[t];
    if (t < H0d) {
        MU0[t] = (double)mu0[t];
        RS0[t] = (double)g0[t] / sqrt((double)va0[t] + 1e-5);
        BE0[t] = (double)be0[t];
    }
    if (t >= 192 && t < 224) {
        int j = t - 192;
        MU1[j] = (double)mu1[j0 + j];
        RS1[j] = (double)g1[j0 + j] / sqrt((double)va1[j0 + j] + 1e-5);
        BE1[j] = (double)be1[j0 + j];
    }
    __syncthreads();

    const int p = (blockIdx.x >> 2) * 256 + t;   // 0..32767  (= b*M + m)
    const double x = (double)coord[p * 3 + 0];
    const double y = (double)coord[p * 3 + 1];
    const double z = (double)coord[p * 3 + 2];
    const double r  = sqrt(x * x + y * y + z * z);
    const double th = acos(z / r);
    const double fi = atan2(y, x);

    double h0[H0d];
    #pragma unroll
    for (int i = 0; i < H0d; i++) {
        double a = x * W0[i] + y * W0[H0d + i] + z * W0[2 * H0d + i]
                 + th * W0[3 * H0d + i] + fi * W0[4 * H0d + i];
        a = (a - MU0[i]) * RS0[i] + BE0[i];
        h0[i] = a > 0.0 ? a : 0.0;
    }
    float* o = h1T + (size_t)(p >> 13) * (H1d * Md) + (p & (Md - 1));
    for (int jc = 0; jc < 32; jc += 2) {
        double a0 = 0.0, a1 = 0.0;
        #pragma unroll
        for (int i = 0; i < H0d; i++) {
            double h = h0[i];
            a0 += h * W1[i * 32 + jc];
            a1 += h * W1[i * 32 + jc + 1];
        }
        a0 = (a0 - MU1[jc]) * RS1[jc] + BE1[jc];             a0 = a0 > 0.0 ? a0 : 0.0;
        a1 = (a1 - MU1[jc + 1]) * RS1[jc + 1] + BE1[jc + 1]; a1 = a1 > 0.0 ? a1 : 0.0;
        o[(size_t)(j0 + jc) * Md]     = (float)a0;
        o[(size_t)(j0 + jc + 1) * Md] = (float)a1;
    }
}

// ---------------------------------------------------------------------------
// K2: f32 GEMM, 128x128 tile, 8x8 per thread, BK=32 x 4 steps (32 KB LDS
// -> 4 blocks/CU). Raw f32 logits out. [round-9-verified verbatim]
// ---------------------------------------------------------------------------
__global__ __launch_bounds__(256, 4) void k2_gemm(
    const float* __restrict__ h1T,
    const float* __restrict__ w2,
    float* __restrict__ logits)
{
    __shared__ float As[32][128];            // 16 KB
    __shared__ float Bs[32][128];            // 16 KB
    const int bx = blockIdx.x, b = blockIdx.y;
    const int mtile = bx & 63, stile = bx >> 6;   // mtile fast: same-A blocks on one XCD
    const int m0 = mtile * 128, s0 = stile * 128;
    const int t = threadIdx.x;
    const int tm = t & 15, tn = t >> 4;

    float acc[8][8] = {};

    for (int kt = 0; kt < 4; kt++) {
        const float* Ag = h1T + ((size_t)b * H1d + kt * 32) * Md + m0;
        const float* Bg = w2 + (size_t)(kt * 32) * Sd + s0;
        #pragma unroll
        for (int i = 0; i < 4; i++) {
            int idx = t + i * 256;
            int kk = idx >> 5, c = idx & 31;
            *(float4*)&As[kk][c * 4] = *(const float4*)&Ag[(size_t)kk * Md + c * 4];
            *(float4*)&Bs[kk][c * 4] = *(const float4*)&Bg[(size_t)kk * Sd + c * 4];
        }
        __syncthreads();

        #pragma unroll 8
        for (int k = 0; k < 32; k++) {
            float a_[8], b_[8];
            *(float4*)&a_[0] = *(const float4*)&As[k][tm * 4];
            *(float4*)&a_[4] = *(const float4*)&As[k][64 + tm * 4];
            *(float4*)&b_[0] = *(const float4*)&Bs[k][tn * 4];
            *(float4*)&b_[4] = *(const float4*)&Bs[k][64 + tn * 4];
            #pragma unroll
            for (int si = 0; si < 8; si++)
                #pragma unroll
                for (int mi = 0; mi < 8; mi++)
                    acc[si][mi] += b_[si] * a_[mi];
        }
        __syncthreads();
    }

    #pragma unroll
    for (int si = 0; si < 8; si++) {
        int s = s0 + (si >> 2) * 64 + tn * 4 + (si & 3);
        float* row = logits + ((size_t)b * Sd + s) * Md + m0;
        *(float4*)&row[tm * 4]      = make_float4(acc[si][0], acc[si][1], acc[si][2], acc[si][3]);
        *(float4*)&row[64 + tm * 4] = make_float4(acc[si][4], acc[si][5], acc[si][6], acc[si][7]);
    }
}

// ---------------------------------------------------------------------------
// K3 (fused): selection + one-hot + gather, one block per (b,s) row.
// [round-9-verified verbatim] Ranking domain = f32 Q = sigmoid(logit) via
// libm expf (matches the reference's f32 comparison domain INCLUDING tie
// structure). Threshold filter + rank-count; guard falls back to iterative
// extraction.
// ---------------------------------------------------------------------------
__global__ __launch_bounds__(256) void k3_fused(
    float* __restrict__ logits,              // row r read, then overwritten with Qg
    const float* __restrict__ gumbel,
    const float* __restrict__ coord,
    const float* __restrict__ feat,
    float* __restrict__ out)
{
    const int r = blockIdx.x;                // 0..4095
    const int b = r >> 10;
    const int t = threadIdx.x;
    const int lane = t & 63, wav = t >> 6;
    const float4* L4 = (const float4*)(logits + (size_t)r * Md);
    const float4* G4 = (const float4*)(gumbel + (size_t)r * Md);

    __shared__ unsigned long long wred[2][4];
    __shared__ unsigned long long ck[CAP];
    __shared__ unsigned swT[4];
    __shared__ int cnt;
    __shared__ int order[32];

    // ---- load + sigmoid + inline gumbel scan (float4, 16B/lane) ----
    unsigned uq[32];
    unsigned gbu = 0u; int gbm = 0;
    #pragma unroll
    for (int j = 0; j < 8; j++) {
        float4 v = L4[j * 256 + t];
        float4 g = G4[j * 256 + t];
        #pragma unroll
        for (int c = 0; c < 4; c++) {
            float x = ((const float*)&v)[c];
            float q = 1.0f / (1.0f + expf(-x));
            uq[j * 4 + c] = f2u(q);          // q>0 -> top bit set; 0 is a safe sentinel
            unsigned us = f2u(q + ((const float*)&g)[c]);
            if (us > gbu) { gbu = us; gbm = j * 1024 + t * 4 + c; }
        }
    }

    // ---- gumbel argmax reduce (first max -> smallest m via inverted-index key) ----
    {
        unsigned long long key = ((unsigned long long)gbu << 32) | (unsigned)(Md - 1 - gbm);
        #pragma unroll
        for (int o = 32; o > 0; o >>= 1) {
            unsigned long long other = __shfl_down(key, o);
            if (other > key) key = other;
        }
        if (lane == 0) wred[0][wav] = key;
    }
    if (t == 0) cnt = 0;
    __syncthreads();                         // B1: wred[0], cnt
    unsigned long long gbest = wred[0][0];
    if (wred[0][1] > gbest) gbest = wred[0][1];
    if (wred[0][2] > gbest) gbest = wred[0][2];
    if (wred[0][3] > gbest) gbest = wred[0][3];
    const int am = Md - 1 - (int)(gbest & 0xFFFFFFFFull);

    // ---- per-thread max, wave bitonic sort of 64 lane-maxima -> threshold T ----
    unsigned pm = 0u;
    #pragma unroll
    for (int i = 0; i < 32; i++) pm = max(pm, uq[i]);
    unsigned v = pm;
    #pragma unroll
    for (int k = 2; k <= 64; k <<= 1) {
        #pragma unroll
        for (int j = k >> 1; j > 0; j >>= 1) {
            unsigned o = __shfl_xor(v, j);
            bool up = ((lane & k) == 0);
            bool lower = ((lane & j) == 0);
            unsigned mn = min(v, o), mx = max(v, o);
            v = (lower == up) ? mn : mx;     // ascending by lane after final pass
        }
    }
    unsigned tw = __shfl(v, 32);             // asc pos 32 = 32nd largest of the wave
    if (lane == 0) swT[wav] = tw;
    __syncthreads();                         // B2: swT
    const unsigned T = max(max(swT[0], swT[1]), max(swT[2], swT[3]));

    // ---- collect candidates >= T ----
    #pragma unroll
    for (int i = 0; i < 32; i++) {
        if (uq[i] >= T) {
            int pos = atomicAdd(&cnt, 1);
            if (pos < CAP) {
                int m = (i >> 2) * 1024 + t * 4 + (i & 3);
                ck[pos] = ((unsigned long long)uq[i] << 32) | (unsigned)(Md - 1 - m);
            }
        }
    }
    __syncthreads();                         // B3: ck, cnt
    const int n = cnt;

    if (n >= 32 && n <= CAP) {
        // ---- fast path: O(n^2) rank-count ----
        for (int j2 = t; j2 < n; j2 += 256) {
            unsigned long long mine = ck[j2];
            int rk = 0;
            for (int i2 = 0; i2 < n; i2++) rk += (ck[i2] > mine) ? 1 : 0;
            if (rk < 32) order[rk] = Md - 1 - (int)(mine & 0xFFFFFFFFull);
        }
    } else {
        // ---- fallback: verified iterative extraction ----
        for (int round = 0; round < 32; round++) {
            unsigned bu = 0u; int bi = 0;
            #pragma unroll
            for (int i = 0; i < 32; i++)
                if (uq[i] > bu) { bu = uq[i]; bi = i; }
            int bm = (bi >> 2) * 1024 + t * 4 + (bi & 3);
            unsigned long long key =
                ((unsigned long long)bu << 32) | (unsigned)(Md - 1 - bm);
            #pragma unroll
            for (int o = 32; o > 0; o >>= 1) {
                unsigned long long other = __shfl_down(key, o);
                if (other > key) key = other;
            }
            const int p = round & 1;
            if (lane == 0) wred[p][wav] = key;
            __syncthreads();
            unsigned long long best = wred[p][0];
            if (wred[p][1] > best) best = wred[p][1];
            if (wred[p][2] > best) best = wred[p][2];
            if (wred[p][3] > best) best = wred[p][3];
            const int m_win = Md - 1 - (int)(best & 0xFFFFFFFFull);
            if (((m_win >> 2) & 255) == t)
                uq[(m_win >> 10) * 4 + (m_win & 3)] = 0u;
            if (t == 0) order[round] = m_win;
        }
    }
    __syncthreads();                         // B4: order[] visible

    // ---- outputs ----
    // Qg one-hot (overwrites this block's own logits row)
    {
        const int q4 = am >> 2;
        float4* row = (float4*)(logits + (size_t)r * Md);
        #pragma unroll
        for (int i = 0; i < 8; i++) {
            int idx = i * 256 + t;
            float4 vv = make_float4(0.f, 0.f, 0.f, 0.f);
            if (idx == q4) ((float*)&vv)[am & 3] = 1.0f;
            row[idx] = vv;
        }
    }
    if (t < 3)
        out[OFF_SP + (size_t)r * 3 + t] = coord[((size_t)b * Md + am) * 3 + t];
    if (t >= 32 && t < 128) {
        int e = t - 32;                      // 0..95
        int nn = e / 3, c = e - nn * 3;
        out[OFF_GP + (size_t)r * 96 + e] = coord[((size_t)b * Md + order[nn]) * 3 + c];
    }
    const float4* F4  = (const float4*)feat;          // feat row = 16 float4
    float4* SF4 = (float4*)(out + OFF_SF);
    float4* GF4 = (float4*)(out + OFF_GF);
    if (t < 16) {
        float4 fv = F4[((size_t)b * Md + am) * 16 + t];
        SF4[(size_t)r * 16 + t]  = fv;       // sampled_feature
        GF4[(size_t)r * 512 + t] = fv;       // grouped_feature[.,.,0,:]
    }
    for (int e4 = 16 + t; e4 < 512; e4 += 256) {
        int nn = e4 >> 4, d4 = e4 & 15;
        GF4[(size_t)r * 512 + e4] = F4[((size_t)b * Md + order[nn]) * 16 + d4];
    }
}

// ---------------------------------------------------------------------------
extern "C" void kernel_launch(void* const* d_in, const int* in_sizes, int n_in,
                              void* d_out, int out_size, void* d_ws, size_t ws_size,
                              hipStream_t stream)
{
    (void)in_sizes; (void)n_in; (void)out_size; (void)d_ws; (void)ws_size;
    const float* coord = (const float*)d_in[0];
    const float* feat  = (const float*)d_in[1];
    const float* gum   = (const float*)d_in[2];
    const float* w0    = (const float*)d_in[3];
    const float* g0    = (const float*)d_in[4];
    const float* be0   = (const float*)d_in[5];
    const float* mu0   = (const float*)d_in[6];
    const float* va0   = (const float*)d_in[7];
    const float* w1    = (const float*)d_in[8];
    const float* g1    = (const float*)d_in[9];
    const float* be1   = (const float*)d_in[10];
    const float* mu1   = (const float*)d_in[11];
    const float* va1   = (const float*)d_in[12];
    const float* w2    = (const float*)d_in[13];

    float*  out    = (float*)d_out;
    float*  h1T    = out + OFF_GF;              // f32 h1T scratch (overwritten by k3 gather)
    float*  logits = out + OFF_QG;              // f32 logits -> Qg one-hot

    k1_mlp   <<<dim3(512),     dim3(256), 0, stream>>>(coord, w0, g0, be0, mu0, va0,
                                                       w1, g1, be1, mu1, va1, h1T);
    k2_gemm  <<<dim3(512, 4),  dim3(256), 0, stream>>>(h1T, w2, logits);
    k3_fused <<<dim3(4096),    dim3(256), 0, stream>>>(logits, gum, coord, feat, out);
}